// Round 10
// baseline (343.345 us; speedup 1.0000x reference)
//
#include <hip/hip_runtime.h>
#include <hip/hip_bf16.h>
#include <cstddef>

// ---------- types / helpers ----------
typedef __attribute__((ext_vector_type(8))) short bf16x8;
typedef __attribute__((ext_vector_type(4))) float f32x4;

static __device__ __forceinline__ unsigned short f2bf(float f) {
    unsigned int u = __float_as_uint(f);
    u += 0x7fffu + ((u >> 16) & 1u);
    return (unsigned short)(u >> 16);
}
static __device__ __forceinline__ float bf2f(unsigned short h) {
    return __uint_as_float(((unsigned int)h) << 16);
}

#define B_ 8
#define S_ 1000
#define H_ 768
#define NH_ 12
#define HD_ 64
#define M_ 8000
#define HC_ 2304   // 3*768

// ---------- kernel 1: fused (x = features + pos*scale -> bf16) + (weights -> bf16) ----------
__global__ __launch_bounds__(256)
void prep_all_kernel(const float* __restrict__ feat, const float* __restrict__ pos,
                     const int* __restrict__ level, unsigned short* __restrict__ xb,
                     const float* __restrict__ wq, const float* __restrict__ wk,
                     const float* __restrict__ wv, const float* __restrict__ wo,
                     unsigned short* __restrict__ wdst) {
    const size_t NX = (size_t)M_ * H_ / 4;
    const size_t WSZ = (size_t)H_ * H_;
    size_t gid = (size_t)blockIdx.x * blockDim.x + threadIdx.x;
    if (gid < NX) {
        size_t e = gid * 4;
        float sc = 1.0f + 0.1f * (float)level[0];
        const float4 f = *reinterpret_cast<const float4*>(&feat[e]);
        size_t pe = e % ((size_t)S_ * H_);
        const float4 p = *reinterpret_cast<const float4*>(&pos[pe]);
        ushort4 o;
        o.x = f2bf(f.x + sc * p.x);
        o.y = f2bf(f.y + sc * p.y);
        o.z = f2bf(f.z + sc * p.z);
        o.w = f2bf(f.w + sc * p.w);
        *reinterpret_cast<ushort4*>(&xb[e]) = o;
    } else {
        size_t e = (gid - NX) * 4;
        if (e >= 4 * WSZ) return;
        const float* src; size_t off;
        if (e < WSZ)          { src = wq; off = e; }
        else if (e < 2 * WSZ) { src = wk; off = e - WSZ; }
        else if (e < 3 * WSZ) { src = wv; off = e - 2 * WSZ; }
        else                  { src = wo; off = e - 3 * WSZ; }
        const float4 f = *reinterpret_cast<const float4*>(&src[off]);
        ushort4 o;
        o.x = f2bf(f.x); o.y = f2bf(f.y); o.z = f2bf(f.z); o.w = f2bf(f.w);
        *reinterpret_cast<ushort4*>(&wdst[e]) = o;
    }
}

// ---------- kernel 2: QKV GEMM, 128x256 tile, 8 waves (2x4), 64x64 wave-tile ----------
// Double-buffered BK=32 (2 x 24KB = 48KB), R5-proven 2-barrier pattern,
// counted vmcnt(3). bounds(512,6) -> 3 blocks/CU -> 567 blocks co-resident
// in ONE generation. Swizzled 64B rows (phys_slot = log ^ ((row>>1)&3);
// pre-swizzled global source, linear gload_lds dest, same XOR on ds_read).
// Swapped-operand MFMA -> thread holds 4 consecutive cols.
__global__ __launch_bounds__(512, 6)
void gemm_qkv4(const unsigned short* __restrict__ A,
               const unsigned short* __restrict__ Bw,
               const float* __restrict__ b0, const float* __restrict__ b1,
               const float* __restrict__ b2,
               unsigned short* __restrict__ outB) {
    const int K = H_;
    __shared__ char lds[49152];                       // 2 x 24KB buffers
    const int tid = threadIdx.x, lane = tid & 63, wid = tid >> 6;
    const int wr = wid >> 2, wc = wid & 3;            // 2 x 4 waves; per-wave 64x64
    const int fr = lane & 15, fq = lane >> 4;

    // bijective XCD swizzle (nwg = 567, not %8)
    const int nwg = gridDim.x;
    const int q = nwg >> 3, r = nwg & 7;
    const int xcd = blockIdx.x & 7, idx = blockIdx.x >> 3;
    const int swz = (xcd < r) ? (xcd * (q + 1) + idx) : (r * (q + 1) + (xcd - r) * q + idx);
    const int ntn = HC_ / 256;                        // 9
    const int bm = (swz / ntn) * 128;
    const int bn = (swz % ntn) * 256;

    const int srow = lane >> 2;
    const int scol = ((lane & 3) ^ ((lane >> 3) & 3)) * 8;   // pre-swizzled source k-offset

    auto stage = [&](int buf, int k0) {
        char* base = lds + buf * 24576;
        // A: 8 chunks of 16 rows; wave w stages chunk w
        int ar = bm + wid * 16 + srow;
        ar = ar < M_ ? ar : M_ - 1;                   // clamp: junk rows -> out-rows >= M (skipped)
        __builtin_amdgcn_global_load_lds(
            (const __attribute__((address_space(1))) unsigned int*)(A + (size_t)ar * K + k0 + scol),
            (__attribute__((address_space(3))) unsigned int*)(base + wid * 1024), 16, 0, 0);
        // B: 16 chunks; wave w stages chunks 2w, 2w+1 (HC_ multiple of 256)
#pragma unroll
        for (int t = 0; t < 2; ++t) {
            const int c = wid * 2 + t;
            const int br = bn + c * 16 + srow;
            __builtin_amdgcn_global_load_lds(
                (const __attribute__((address_space(1))) unsigned int*)(Bw + (size_t)br * K + k0 + scol),
                (__attribute__((address_space(3))) unsigned int*)(base + 8192 + c * 1024), 16, 0, 0);
        }
    };

    f32x4 acc[4][4] = {};
    const int rsl = fq ^ ((fr >> 1) & 3);
    const int NT = K / 32;                            // 24

    stage(0, 0);                                      // 3 loads/wave in flight
    for (int t = 0; t < NT; ++t) {
        const int cur = t & 1;
        if (t + 1 < NT) {
            stage(cur ^ 1, (t + 1) * 32);             // +3 -> 6 outstanding
            asm volatile("s_waitcnt vmcnt(3)" ::: "memory");   // oldest 3 (tile t) landed
        } else {
            asm volatile("s_waitcnt vmcnt(0)" ::: "memory");
        }
        __builtin_amdgcn_s_barrier();                 // tile t visible to all waves

        char* base = lds + cur * 24576;
        bf16x8 af[4], bfv[4];
#pragma unroll
        for (int m = 0; m < 4; ++m) {
            const int row = wr * 64 + m * 16 + fr;
            af[m] = *reinterpret_cast<const bf16x8*>(base + row * 64 + rsl * 16);
        }
#pragma unroll
        for (int n = 0; n < 4; ++n) {
            const int row = wc * 64 + n * 16 + fr;
            bfv[n] = *reinterpret_cast<const bf16x8*>(base + 8192 + row * 64 + rsl * 16);
        }
        __builtin_amdgcn_s_setprio(1);
#pragma unroll
        for (int m = 0; m < 4; ++m)
#pragma unroll
            for (int n = 0; n < 4; ++n)
                acc[m][n] = __builtin_amdgcn_mfma_f32_16x16x32_bf16(bfv[n], af[m], acc[m][n], 0, 0, 0);
        __builtin_amdgcn_s_setprio(0);
        __builtin_amdgcn_s_barrier();                 // reads done before buffer reuse
    }

    // epilogue: row = bm + wr*64 + m*16 + fr, col = bn + wc*64 + n*16 + fq*4 + j
    const int colg = (bn < 768) ? bn : (bn < 1536) ? bn - 768 : bn - 1536;
    const float* bsel = (bn < 768) ? b0 : (bn < 1536) ? b1 : b2;
#pragma unroll
    for (int m = 0; m < 4; ++m) {
        const int row = bm + wr * 64 + m * 16 + fr;
        if (row >= M_) continue;
#pragma unroll
        for (int n = 0; n < 4; ++n) {
            const int cb = wc * 64 + n * 16 + fq * 4;
            const float4 bv = *reinterpret_cast<const float4*>(&bsel[colg + cb]);
            ushort4 o;
            o.x = f2bf(acc[m][n][0] + bv.x);
            o.y = f2bf(acc[m][n][1] + bv.y);
            o.z = f2bf(acc[m][n][2] + bv.z);
            o.w = f2bf(acc[m][n][3] + bv.w);
            *reinterpret_cast<ushort4*>(&outB[(size_t)row * HC_ + bn + cb]) = o;
        }
    }
}

// ---------- kernel 4: FUSED out-proj + residual + LayerNorm ----------
// Block = 32 rows x ALL 768 cols (grid exactly 250, no tail). 8 waves, each
// owning a 32x96 col-slice (acc 48 f32). Double-buffered staging: A tile 2KB
// + full-width Wo tile 48KB per buffer. Per-wave load counts differ (7 vs 6)
// -> per-wave-uniform vmcnt. After K-loop: y = acc + bo + resid in regs,
// per-row mean/var via fq-shuffle + cross-wave LDS reduce, single fp32 store.
__global__ __launch_bounds__(512)
void gemm_out_ln(const unsigned short* __restrict__ A,   // ctx [8000][768]
                 const unsigned short* __restrict__ Bw,  // Wo [768][768]
                 const float* __restrict__ bo,
                 const float* __restrict__ resid,
                 const float* __restrict__ g, const float* __restrict__ lnb,
                 float* __restrict__ outF) {
    const int K = H_;
    __shared__ char lds[102400];                      // 2 x (2KB A + 48KB B)
    __shared__ float sred[8][2][16][2];               // [wave][m][fr][sum,sumsq]
    const int tid = threadIdx.x, lane = tid & 63, wid = tid >> 6;
    const int fr = lane & 15, fq = lane >> 4;
    const int bm = blockIdx.x * 32;                   // 8000 = 250*32, no tail

    const int srow = lane >> 2;
    const int scol = ((lane & 3) ^ ((lane >> 3) & 3)) * 8;

    auto stage = [&](int buf, int k0) {
        char* base = lds + buf * 51200;
        if (wid < 2) {                                // A: 2 chunks of 16 rows
            const int ar = bm + wid * 16 + srow;
            __builtin_amdgcn_global_load_lds(
                (const __attribute__((address_space(1))) unsigned int*)(A + (size_t)ar * K + k0 + scol),
                (__attribute__((address_space(3))) unsigned int*)(base + wid * 1024), 16, 0, 0);
        }
#pragma unroll
        for (int t = 0; t < 6; ++t) {                 // B: 48 chunks, 6 per wave
            const int c = wid * 6 + t;
            const int br = c * 16 + srow;             // 768 rows total
            __builtin_amdgcn_global_load_lds(
                (const __attribute__((address_space(1))) unsigned int*)(Bw + (size_t)br * K + k0 + scol),
                (__attribute__((address_space(3))) unsigned int*)(base + 2048 + c * 1024), 16, 0, 0);
        }
    };

    f32x4 acc[2][6] = {};
    const int rsl = fq ^ ((fr >> 1) & 3);
    const int NT = K / 32;                            // 24

    stage(0, 0);
    for (int t = 0; t < NT; ++t) {
        const int cur = t & 1;
        if (t + 1 < NT) {
            stage(cur ^ 1, (t + 1) * 32);
            if (wid < 2) { asm volatile("s_waitcnt vmcnt(7)" ::: "memory"); }
            else         { asm volatile("s_waitcnt vmcnt(6)" ::: "memory"); }
        } else {
            asm volatile("s_waitcnt vmcnt(0)" ::: "memory");
        }
        __builtin_amdgcn_s_barrier();

        char* base = lds + cur * 51200;
        bf16x8 af[2], bfv[6];
#pragma unroll
        for (int m = 0; m < 2; ++m) {
            const int row = m * 16 + fr;
            af[m] = *reinterpret_cast<const bf16x8*>(base + row * 64 + rsl * 16);
        }
#pragma unroll
        for (int n = 0; n < 6; ++n) {
            const int row = wid * 96 + n * 16 + fr;
            bfv[n] = *reinterpret_cast<const bf16x8*>(base + 2048 + row * 64 + rsl * 16);
        }
        __builtin_amdgcn_s_setprio(1);
#pragma unroll
        for (int m = 0; m < 2; ++m)
#pragma unroll
            for (int n = 0; n < 6; ++n)
                acc[m][n] = __builtin_amdgcn_mfma_f32_16x16x32_bf16(bfv[n], af[m], acc[m][n], 0, 0, 0);
        __builtin_amdgcn_s_setprio(0);
        __builtin_amdgcn_s_barrier();
    }

    // ---- epilogue: y = acc + bo + resid; per-row LN over 768 cols ----
    float s[2] = {0.f, 0.f}, sq[2] = {0.f, 0.f};
#pragma unroll
    for (int m = 0; m < 2; ++m) {
        const int row = bm + m * 16 + fr;
#pragma unroll
        for (int n = 0; n < 6; ++n) {
            const int col = wid * 96 + n * 16 + fq * 4;
            const float4 bv = *reinterpret_cast<const float4*>(&bo[col]);
            const float4 rv = *reinterpret_cast<const float4*>(&resid[(size_t)row * H_ + col]);
            acc[m][n][0] += bv.x + rv.x;
            acc[m][n][1] += bv.y + rv.y;
            acc[m][n][2] += bv.z + rv.z;
            acc[m][n][3] += bv.w + rv.w;
#pragma unroll
            for (int j = 0; j < 4; ++j) {
                s[m]  += acc[m][n][j];
                sq[m] += acc[m][n][j] * acc[m][n][j];
            }
        }
    }
    // reduce across fq (lanes fq*16+fr share rows): xor 16, 32
#pragma unroll
    for (int m = 0; m < 2; ++m) {
        s[m]  += __shfl_xor(s[m], 16);  s[m]  += __shfl_xor(s[m], 32);
        sq[m] += __shfl_xor(sq[m], 16); sq[m] += __shfl_xor(sq[m], 32);
    }
    if (fq == 0) {
#pragma unroll
        for (int m = 0; m < 2; ++m) { sred[wid][m][fr][0] = s[m]; sred[wid][m][fr][1] = sq[m]; }
    }
    __syncthreads();
    float mu[2], rs[2];
#pragma unroll
    for (int m = 0; m < 2; ++m) {
        float S = 0.f, Q = 0.f;
#pragma unroll
        for (int w = 0; w < 8; ++w) { S += sred[w][m][fr][0]; Q += sred[w][m][fr][1]; }
        mu[m] = S * (1.f / H_);
        float var = Q * (1.f / H_) - mu[m] * mu[m];
        rs[m] = rsqrtf(var + 1e-5f);
    }
#pragma unroll
    for (int m = 0; m < 2; ++m) {
        const int row = bm + m * 16 + fr;
#pragma unroll
        for (int n = 0; n < 6; ++n) {
            const int col = wid * 96 + n * 16 + fq * 4;
            const float4 gv = *reinterpret_cast<const float4*>(&g[col]);
            const float4 bb = *reinterpret_cast<const float4*>(&lnb[col]);
            float4 ov;
            ov.x = (acc[m][n][0] - mu[m]) * rs[m] * gv.x + bb.x;
            ov.y = (acc[m][n][1] - mu[m]) * rs[m] * gv.y + bb.y;
            ov.z = (acc[m][n][2] - mu[m]) * rs[m] * gv.z + bb.z;
            ov.w = (acc[m][n][3] - mu[m]) * rs[m] * gv.w + bb.w;
            *reinterpret_cast<float4*>(&outF[(size_t)row * H_ + col]) = ov;
        }
    }
}

// ---------- kernel 3: banded attention, 16 queries/wave, 4 lanes x 16 dims ----------
__global__ __launch_bounds__(256)
void attn_kernel(const unsigned short* __restrict__ QKV,
                 unsigned short* __restrict__ ctx,
                 const int* __restrict__ level_p) {
    const int lane = threadIdx.x & 63;
    const int wv = threadIdx.x >> 6;
    const int qiw = lane >> 2;
    const int d0 = (lane & 3) * 16;

    const int qt = blockIdx.x & 15;
    const int h  = (blockIdx.x >> 4) % NH_;
    const int b  = blockIdx.x / (16 * NH_);
    const int i  = qt * 64 + wv * 16 + qiw;
    const bool valid = i < S_;
    const int iq = valid ? i : S_ - 1;

    const int lev = level_p[0];
    const int w = (lev == 0) ? 2 : (lev == 1) ? 5 : S_;

    const size_t qoff = (size_t)(b * S_ + iq) * HC_ + h * HD_ + d0;
    bf16x8 qa = *reinterpret_cast<const bf16x8*>(&QKV[qoff]);
    bf16x8 qb = *reinterpret_cast<const bf16x8*>(&QKV[qoff + 8]);
    float qf[16];
#pragma unroll
    for (int t = 0; t < 8; ++t) {
        qf[t]     = bf2f((unsigned short)qa[t]);
        qf[t + 8] = bf2f((unsigned short)qb[t]);
    }

    const int j0 = max(0, i - w), j1 = min(S_ - 1, i + w);
    float mx = -1e30f, l = 0.f;
    float acc[16];
#pragma unroll
    for (int t = 0; t < 16; ++t) acc[t] = 0.f;

    for (int jc = j0; jc <= j1; jc += 5) {
        float s[5];
        int jj[5];
#pragma unroll
        for (int t = 0; t < 5; ++t) {
            const int j = jc + t;
            jj[t] = j <= j1 ? j : j1;
            const size_t koff = (size_t)(b * S_ + jj[t]) * HC_ + 768 + h * HD_ + d0;
            bf16x8 ka = *reinterpret_cast<const bf16x8*>(&QKV[koff]);
            bf16x8 kb = *reinterpret_cast<const bf16x8*>(&QKV[koff + 8]);
            float p = 0.f;
#pragma unroll
            for (int d = 0; d < 8; ++d) {
                p = fmaf(qf[d], bf2f((unsigned short)ka[d]), p);
                p = fmaf(qf[d + 8], bf2f((unsigned short)kb[d]), p);
            }
            s[t] = p;
        }
#pragma unroll
        for (int t = 0; t < 5; ++t) s[t] += __shfl_xor(s[t], 1);
#pragma unroll
        for (int t = 0; t < 5; ++t) s[t] += __shfl_xor(s[t], 2);
#pragma unroll
        for (int t = 0; t < 5; ++t)
            s[t] = (jc + t <= j1) ? s[t] * 0.125f : -1e30f;

        float cm = fmaxf(fmaxf(fmaxf(s[0], s[1]), fmaxf(s[2], s[3])), s[4]);
        float nm = fmaxf(mx, cm);
        float corr = __expf(mx - nm);
        l *= corr;
#pragma unroll
        for (int t = 0; t < 16; ++t) acc[t] *= corr;
#pragma unroll
        for (int t = 0; t < 5; ++t) {
            const float e = __expf(s[t] - nm);
            l += e;
            const size_t voff = (size_t)(b * S_ + jj[t]) * HC_ + 1536 + h * HD_ + d0;
            bf16x8 va = *reinterpret_cast<const bf16x8*>(&QKV[voff]);
            bf16x8 vb = *reinterpret_cast<const bf16x8*>(&QKV[voff + 8]);
#pragma unroll
            for (int d = 0; d < 8; ++d) {
                acc[d]     = fmaf(e, bf2f((unsigned short)va[d]), acc[d]);
                acc[d + 8] = fmaf(e, bf2f((unsigned short)vb[d]), acc[d + 8]);
            }
        }
        mx = nm;
    }

    if (valid) {
        const float inv = 1.f / l;
        bf16x8 o0, o1;
#pragma unroll
        for (int t = 0; t < 8; ++t) {
            o0[t] = (short)f2bf(acc[t] * inv);
            o1[t] = (short)f2bf(acc[t + 8] * inv);
        }
        unsigned short* dst = &ctx[(size_t)(b * S_ + i) * H_ + h * HD_ + d0];
        *reinterpret_cast<bf16x8*>(dst) = o0;
        *reinterpret_cast<bf16x8*>(dst + 8) = o1;
    }
}

// ---------- launch ----------
extern "C" void kernel_launch(void* const* d_in, const int* in_sizes, int n_in,
                              void* d_out, int out_size, void* d_ws, size_t ws_size,
                              hipStream_t stream) {
    const float* feat  = (const float*)d_in[0];
    const float* pos   = (const float*)d_in[1];
    const float* Wq    = (const float*)d_in[2];
    const float* bq    = (const float*)d_in[3];
    const float* Wk    = (const float*)d_in[4];
    const float* bk    = (const float*)d_in[5];
    const float* Wv    = (const float*)d_in[6];
    const float* bv    = (const float*)d_in[7];
    const float* Wo    = (const float*)d_in[8];
    const float* bo    = (const float*)d_in[9];
    const float* ln_g  = (const float*)d_in[10];
    const float* ln_b  = (const float*)d_in[11];
    const int*   level = (const int*)d_in[12];
    float* out = (float*)d_out;

    char* ws = (char*)d_ws;
    unsigned short* xb   = (unsigned short*)ws;                      // [8000][768]
    unsigned short* Wcat = xb + (size_t)M_ * H_;                     // [3072][768] = Wq|Wk|Wv|Wo
    unsigned short* QKVb = Wcat + (size_t)4 * H_ * H_;               // [8000][2304]
    unsigned short* ctxb = QKVb + (size_t)M_ * HC_;                  // [8000][768]

    // 1) fused x-prep + weight cast
    const int nprep = (int)(((size_t)M_ * H_ / 4 + (size_t)4 * H_ * H_ / 4 + 255) / 256);
    prep_all_kernel<<<nprep, 256, 0, stream>>>(feat, pos, level, xb, Wq, Wk, Wv, Wo, Wcat);
    // 2) QKV = x @ [Wq|Wk|Wv]^T + bias   (grid 63x9 = 567, 512 thr, 3 blk/CU)
    gemm_qkv4<<<63 * 9, 512, 0, stream>>>(xb, Wcat, bq, bk, bv, QKVb);
    // 3) banded attention -> ctx (bf16)
    attn_kernel<<<B_ * NH_ * 16, 256, 0, stream>>>(QKVb, ctxb, level);
    // 4) y = LN(ctx @ Wo^T + bo + features)  (fused, grid 250, 512 thr)
    gemm_out_ln<<<250, 512, 0, stream>>>(ctxb, Wcat + (size_t)3 * H_ * H_, bo, feat,
                                         ln_g, ln_b, out);
}

// Round 11
// 117.438 us; speedup vs baseline: 2.9236x; 2.9236x over previous
//
#include <hip/hip_runtime.h>
#include <hip/hip_bf16.h>
#include <cstddef>

// ---------- types / helpers ----------
typedef __attribute__((ext_vector_type(8))) short bf16x8;
typedef __attribute__((ext_vector_type(4))) float f32x4;

static __device__ __forceinline__ unsigned short f2bf(float f) {
    unsigned int u = __float_as_uint(f);
    u += 0x7fffu + ((u >> 16) & 1u);
    return (unsigned short)(u >> 16);
}
static __device__ __forceinline__ float bf2f(unsigned short h) {
    return __uint_as_float(((unsigned int)h) << 16);
}

#define B_ 8
#define S_ 1000
#define H_ 768
#define NH_ 12
#define HD_ 64
#define M_ 8000
#define HC_ 2304   // 3*768

// ---------- kernel 1: fused (x = features + pos*scale -> bf16) + (weights -> bf16) ----------
__global__ __launch_bounds__(256)
void prep_all_kernel(const float* __restrict__ feat, const float* __restrict__ pos,
                     const int* __restrict__ level, unsigned short* __restrict__ xb,
                     const float* __restrict__ wq, const float* __restrict__ wk,
                     const float* __restrict__ wv, const float* __restrict__ wo,
                     unsigned short* __restrict__ wdst) {
    const size_t NX = (size_t)M_ * H_ / 4;
    const size_t WSZ = (size_t)H_ * H_;
    size_t gid = (size_t)blockIdx.x * blockDim.x + threadIdx.x;
    if (gid < NX) {
        size_t e = gid * 4;
        float sc = 1.0f + 0.1f * (float)level[0];
        const float4 f = *reinterpret_cast<const float4*>(&feat[e]);
        size_t pe = e % ((size_t)S_ * H_);
        const float4 p = *reinterpret_cast<const float4*>(&pos[pe]);
        ushort4 o;
        o.x = f2bf(f.x + sc * p.x);
        o.y = f2bf(f.y + sc * p.y);
        o.z = f2bf(f.z + sc * p.z);
        o.w = f2bf(f.w + sc * p.w);
        *reinterpret_cast<ushort4*>(&xb[e]) = o;
    } else {
        size_t e = (gid - NX) * 4;
        if (e >= 4 * WSZ) return;
        const float* src; size_t off;
        if (e < WSZ)          { src = wq; off = e; }
        else if (e < 2 * WSZ) { src = wk; off = e - WSZ; }
        else if (e < 3 * WSZ) { src = wv; off = e - 2 * WSZ; }
        else                  { src = wo; off = e - 3 * WSZ; }
        const float4 f = *reinterpret_cast<const float4*>(&src[off]);
        ushort4 o;
        o.x = f2bf(f.x); o.y = f2bf(f.y); o.z = f2bf(f.z); o.w = f2bf(f.w);
        *reinterpret_cast<ushort4*>(&wdst[e]) = o;
    }
}

// ---------- kernel 2: QKV GEMM, 128x128 tile, 8 waves (2x4), 64x32 wave-tile ----------
// BK=64 per barrier-pair: each 32KB buffer = two 16KB sub-tiles (the proven
// swizzled [128rows][32k] 64B-row layout each). Double-buffered, counted
// vmcnt(4), 12 barrier-pairs (vs 24). bounds(512,4): VGPR cap 128 (no spill,
// kernel ~64), 2 blocks/CU (64KB LDS). Swizzle: phys_slot = log ^ ((row>>1)&3)
// pre-applied on the global source; linear gload_lds dest; same XOR on ds_read.
// Swapped-operand MFMA -> thread holds 4 consecutive cols -> ushort4 stores.
__global__ __launch_bounds__(512, 4)
void gemm_qkv5(const unsigned short* __restrict__ A,
               const unsigned short* __restrict__ Bw,
               const float* __restrict__ b0, const float* __restrict__ b1,
               const float* __restrict__ b2,
               unsigned short* __restrict__ outB) {
    const int K = H_;
    __shared__ char lds[65536];                       // 2 buffers x 2 sub-tiles x 16KB
    const int tid = threadIdx.x, lane = tid & 63, wid = tid >> 6;
    const int wr = wid >> 2, wc = wid & 3;            // 2 x 4 waves; per-wave 64x32
    const int fr = lane & 15, fq = lane >> 4;

    // bijective XCD swizzle (nwg = 1134, not %8)
    const int nwg = gridDim.x;
    const int q = nwg >> 3, r = nwg & 7;
    const int xcd = blockIdx.x & 7, idx = blockIdx.x >> 3;
    const int swz = (xcd < r) ? (xcd * (q + 1) + idx) : (r * (q + 1) + (xcd - r) * q + idx);
    const int ntn = HC_ / 128;                        // 18
    const int bm = (swz / ntn) * 128;
    const int bn = (swz % ntn) * 128;

    const int srow = lane >> 2;
    const int scol = ((lane & 3) ^ ((lane >> 3) & 3)) * 8;   // pre-swizzled source k-offset

    // stage one BK=64 tile = 2 sub-tiles; 4 loads/wave
    auto stage = [&](int buf, int k0) {
        char* base = lds + buf * 32768;
#pragma unroll
        for (int s = 0; s < 2; ++s) {
            char* half = base + s * 16384;
            const int kk = k0 + s * 32;
            int ar = bm + wid * 16 + srow;            // 8 chunks of 16 rows; wave w -> chunk w
            ar = ar < M_ ? ar : M_ - 1;               // clamp: junk rows -> out-rows >= M (skipped)
            __builtin_amdgcn_global_load_lds(
                (const __attribute__((address_space(1))) unsigned int*)(A + (size_t)ar * K + kk + scol),
                (__attribute__((address_space(3))) unsigned int*)(half + wid * 1024), 16, 0, 0);
            const int br = bn + wid * 16 + srow;      // HC_ multiple of 128
            __builtin_amdgcn_global_load_lds(
                (const __attribute__((address_space(1))) unsigned int*)(Bw + (size_t)br * K + kk + scol),
                (__attribute__((address_space(3))) unsigned int*)(half + 8192 + wid * 1024), 16, 0, 0);
        }
    };

    f32x4 acc[4][2] = {};
    const int rsl = fq ^ ((fr >> 1) & 3);
    const int NT = K / 64;                            // 12

    stage(0, 0);                                      // 4 loads/wave in flight
    for (int t = 0; t < NT; ++t) {
        const int cur = t & 1;
        if (t + 1 < NT) {
            stage(cur ^ 1, (t + 1) * 64);             // +4 -> 8 outstanding
            asm volatile("s_waitcnt vmcnt(4)" ::: "memory");   // oldest 4 (tile t) landed
        } else {
            asm volatile("s_waitcnt vmcnt(0)" ::: "memory");
        }
        __builtin_amdgcn_s_barrier();                 // tile t visible to all waves

        char* base = lds + cur * 32768;
#pragma unroll
        for (int s = 0; s < 2; ++s) {                 // two 32-k sub-steps per barrier-pair
            char* half = base + s * 16384;
            bf16x8 af[4], bfv[2];
#pragma unroll
            for (int m = 0; m < 4; ++m) {
                const int row = wr * 64 + m * 16 + fr;
                af[m] = *reinterpret_cast<const bf16x8*>(half + row * 64 + rsl * 16);
            }
#pragma unroll
            for (int n = 0; n < 2; ++n) {
                const int row = wc * 32 + n * 16 + fr;
                bfv[n] = *reinterpret_cast<const bf16x8*>(half + 8192 + row * 64 + rsl * 16);
            }
            __builtin_amdgcn_s_setprio(1);
#pragma unroll
            for (int m = 0; m < 4; ++m)
#pragma unroll
                for (int n = 0; n < 2; ++n)
                    acc[m][n] = __builtin_amdgcn_mfma_f32_16x16x32_bf16(bfv[n], af[m], acc[m][n], 0, 0, 0);
            __builtin_amdgcn_s_setprio(0);
        }
        __builtin_amdgcn_s_barrier();                 // reads done before buffer reuse
    }

    // epilogue: row = bm + wr*64 + m*16 + fr (thread-fixed), col = bn + wc*32 + n*16 + fq*4 + j
    const int colg = (bn < 768) ? bn : (bn < 1536) ? bn - 768 : bn - 1536;
    const float* bsel = (bn < 768) ? b0 : (bn < 1536) ? b1 : b2;
#pragma unroll
    for (int m = 0; m < 4; ++m) {
        const int row = bm + wr * 64 + m * 16 + fr;
        if (row >= M_) continue;
#pragma unroll
        for (int n = 0; n < 2; ++n) {
            const int cb = wc * 32 + n * 16 + fq * 4;
            const float4 bv = *reinterpret_cast<const float4*>(&bsel[colg + cb]);
            ushort4 o;
            o.x = f2bf(acc[m][n][0] + bv.x);
            o.y = f2bf(acc[m][n][1] + bv.y);
            o.z = f2bf(acc[m][n][2] + bv.z);
            o.w = f2bf(acc[m][n][3] + bv.w);
            *reinterpret_cast<ushort4*>(&outB[(size_t)row * HC_ + bn + cb]) = o;
        }
    }
}

// ---------- kernel 4: FUSED out-proj + residual + LayerNorm ----------
// Block = 32 rows x ALL 768 cols (grid exactly 250). 8 waves, each a 32x96
// col-slice. Double-buffered staging (A 2KB + Wo 48KB per buffer), per-wave-
// uniform counted vmcnt. Epilogue: y = acc + bo + resid in regs, per-row
// mean/var via fq-shuffle + cross-wave LDS reduce, single fp32 store.
__global__ __launch_bounds__(512)
void gemm_out_ln(const unsigned short* __restrict__ A,   // ctx [8000][768]
                 const unsigned short* __restrict__ Bw,  // Wo [768][768]
                 const float* __restrict__ bo,
                 const float* __restrict__ resid,
                 const float* __restrict__ g, const float* __restrict__ lnb,
                 float* __restrict__ outF) {
    const int K = H_;
    __shared__ char lds[102400];                      // 2 x (2KB A + 48KB B)
    __shared__ float sred[8][2][16][2];               // [wave][m][fr][sum,sumsq]
    const int tid = threadIdx.x, lane = tid & 63, wid = tid >> 6;
    const int fr = lane & 15, fq = lane >> 4;
    const int bm = blockIdx.x * 32;                   // 8000 = 250*32, no tail

    const int srow = lane >> 2;
    const int scol = ((lane & 3) ^ ((lane >> 3) & 3)) * 8;

    auto stage = [&](int buf, int k0) {
        char* base = lds + buf * 51200;
        if (wid < 2) {                                // A: 2 chunks of 16 rows
            const int ar = bm + wid * 16 + srow;
            __builtin_amdgcn_global_load_lds(
                (const __attribute__((address_space(1))) unsigned int*)(A + (size_t)ar * K + k0 + scol),
                (__attribute__((address_space(3))) unsigned int*)(base + wid * 1024), 16, 0, 0);
        }
#pragma unroll
        for (int t = 0; t < 6; ++t) {                 // B: 48 chunks, 6 per wave
            const int c = wid * 6 + t;
            const int br = c * 16 + srow;             // 768 rows total
            __builtin_amdgcn_global_load_lds(
                (const __attribute__((address_space(1))) unsigned int*)(Bw + (size_t)br * K + k0 + scol),
                (__attribute__((address_space(3))) unsigned int*)(base + 2048 + c * 1024), 16, 0, 0);
        }
    };

    f32x4 acc[2][6] = {};
    const int rsl = fq ^ ((fr >> 1) & 3);
    const int NT = K / 32;                            // 24

    stage(0, 0);
    for (int t = 0; t < NT; ++t) {
        const int cur = t & 1;
        if (t + 1 < NT) {
            stage(cur ^ 1, (t + 1) * 32);
            if (wid < 2) { asm volatile("s_waitcnt vmcnt(7)" ::: "memory"); }
            else         { asm volatile("s_waitcnt vmcnt(6)" ::: "memory"); }
        } else {
            asm volatile("s_waitcnt vmcnt(0)" ::: "memory");
        }
        __builtin_amdgcn_s_barrier();

        char* base = lds + cur * 51200;
        bf16x8 af[2], bfv[6];
#pragma unroll
        for (int m = 0; m < 2; ++m) {
            const int row = m * 16 + fr;
            af[m] = *reinterpret_cast<const bf16x8*>(base + row * 64 + rsl * 16);
        }
#pragma unroll
        for (int n = 0; n < 6; ++n) {
            const int row = wid * 96 + n * 16 + fr;
            bfv[n] = *reinterpret_cast<const bf16x8*>(base + 2048 + row * 64 + rsl * 16);
        }
        __builtin_amdgcn_s_setprio(1);
#pragma unroll
        for (int m = 0; m < 2; ++m)
#pragma unroll
            for (int n = 0; n < 6; ++n)
                acc[m][n] = __builtin_amdgcn_mfma_f32_16x16x32_bf16(bfv[n], af[m], acc[m][n], 0, 0, 0);
        __builtin_amdgcn_s_setprio(0);
        __builtin_amdgcn_s_barrier();
    }

    // ---- epilogue: y = acc + bo + resid; per-row LN over 768 cols ----
    float s[2] = {0.f, 0.f}, sq[2] = {0.f, 0.f};
#pragma unroll
    for (int m = 0; m < 2; ++m) {
        const int row = bm + m * 16 + fr;
#pragma unroll
        for (int n = 0; n < 6; ++n) {
            const int col = wid * 96 + n * 16 + fq * 4;
            const float4 bv = *reinterpret_cast<const float4*>(&bo[col]);
            const float4 rv = *reinterpret_cast<const float4*>(&resid[(size_t)row * H_ + col]);
            acc[m][n][0] += bv.x + rv.x;
            acc[m][n][1] += bv.y + rv.y;
            acc[m][n][2] += bv.z + rv.z;
            acc[m][n][3] += bv.w + rv.w;
#pragma unroll
            for (int j = 0; j < 4; ++j) {
                s[m]  += acc[m][n][j];
                sq[m] += acc[m][n][j] * acc[m][n][j];
            }
        }
    }
    // reduce across fq (lanes fq*16+fr share rows): xor 16, 32
#pragma unroll
    for (int m = 0; m < 2; ++m) {
        s[m]  += __shfl_xor(s[m], 16);  s[m]  += __shfl_xor(s[m], 32);
        sq[m] += __shfl_xor(sq[m], 16); sq[m] += __shfl_xor(sq[m], 32);
    }
    if (fq == 0) {
#pragma unroll
        for (int m = 0; m < 2; ++m) { sred[wid][m][fr][0] = s[m]; sred[wid][m][fr][1] = sq[m]; }
    }
    __syncthreads();
    float mu[2], rs[2];
#pragma unroll
    for (int m = 0; m < 2; ++m) {
        float S = 0.f, Q = 0.f;
#pragma unroll
        for (int w = 0; w < 8; ++w) { S += sred[w][m][fr][0]; Q += sred[w][m][fr][1]; }
        mu[m] = S * (1.f / H_);
        float var = Q * (1.f / H_) - mu[m] * mu[m];
        rs[m] = rsqrtf(var + 1e-5f);
    }
#pragma unroll
    for (int m = 0; m < 2; ++m) {
        const int row = bm + m * 16 + fr;
#pragma unroll
        for (int n = 0; n < 6; ++n) {
            const int col = wid * 96 + n * 16 + fq * 4;
            const float4 gv = *reinterpret_cast<const float4*>(&g[col]);
            const float4 bb = *reinterpret_cast<const float4*>(&lnb[col]);
            float4 ov;
            ov.x = (acc[m][n][0] - mu[m]) * rs[m] * gv.x + bb.x;
            ov.y = (acc[m][n][1] - mu[m]) * rs[m] * gv.y + bb.y;
            ov.z = (acc[m][n][2] - mu[m]) * rs[m] * gv.z + bb.z;
            ov.w = (acc[m][n][3] - mu[m]) * rs[m] * gv.w + bb.w;
            *reinterpret_cast<float4*>(&outF[(size_t)row * H_ + col]) = ov;
        }
    }
}

// ---------- kernel 3: banded attention, 16 queries/wave, 4 lanes x 16 dims ----------
__global__ __launch_bounds__(256)
void attn_kernel(const unsigned short* __restrict__ QKV,
                 unsigned short* __restrict__ ctx,
                 const int* __restrict__ level_p) {
    const int lane = threadIdx.x & 63;
    const int wv = threadIdx.x >> 6;
    const int qiw = lane >> 2;
    const int d0 = (lane & 3) * 16;

    const int qt = blockIdx.x & 15;
    const int h  = (blockIdx.x >> 4) % NH_;
    const int b  = blockIdx.x / (16 * NH_);
    const int i  = qt * 64 + wv * 16 + qiw;
    const bool valid = i < S_;
    const int iq = valid ? i : S_ - 1;

    const int lev = level_p[0];
    const int w = (lev == 0) ? 2 : (lev == 1) ? 5 : S_;

    const size_t qoff = (size_t)(b * S_ + iq) * HC_ + h * HD_ + d0;
    bf16x8 qa = *reinterpret_cast<const bf16x8*>(&QKV[qoff]);
    bf16x8 qb = *reinterpret_cast<const bf16x8*>(&QKV[qoff + 8]);
    float qf[16];
#pragma unroll
    for (int t = 0; t < 8; ++t) {
        qf[t]     = bf2f((unsigned short)qa[t]);
        qf[t + 8] = bf2f((unsigned short)qb[t]);
    }

    const int j0 = max(0, i - w), j1 = min(S_ - 1, i + w);
    float mx = -1e30f, l = 0.f;
    float acc[16];
#pragma unroll
    for (int t = 0; t < 16; ++t) acc[t] = 0.f;

    for (int jc = j0; jc <= j1; jc += 5) {
        float s[5];
        int jj[5];
#pragma unroll
        for (int t = 0; t < 5; ++t) {
            const int j = jc + t;
            jj[t] = j <= j1 ? j : j1;
            const size_t koff = (size_t)(b * S_ + jj[t]) * HC_ + 768 + h * HD_ + d0;
            bf16x8 ka = *reinterpret_cast<const bf16x8*>(&QKV[koff]);
            bf16x8 kb = *reinterpret_cast<const bf16x8*>(&QKV[koff + 8]);
            float p = 0.f;
#pragma unroll
            for (int d = 0; d < 8; ++d) {
                p = fmaf(qf[d], bf2f((unsigned short)ka[d]), p);
                p = fmaf(qf[d + 8], bf2f((unsigned short)kb[d]), p);
            }
            s[t] = p;
        }
#pragma unroll
        for (int t = 0; t < 5; ++t) s[t] += __shfl_xor(s[t], 1);
#pragma unroll
        for (int t = 0; t < 5; ++t) s[t] += __shfl_xor(s[t], 2);
#pragma unroll
        for (int t = 0; t < 5; ++t)
            s[t] = (jc + t <= j1) ? s[t] * 0.125f : -1e30f;

        float cm = fmaxf(fmaxf(fmaxf(s[0], s[1]), fmaxf(s[2], s[3])), s[4]);
        float nm = fmaxf(mx, cm);
        float corr = __expf(mx - nm);
        l *= corr;
#pragma unroll
        for (int t = 0; t < 16; ++t) acc[t] *= corr;
#pragma unroll
        for (int t = 0; t < 5; ++t) {
            const float e = __expf(s[t] - nm);
            l += e;
            const size_t voff = (size_t)(b * S_ + jj[t]) * HC_ + 1536 + h * HD_ + d0;
            bf16x8 va = *reinterpret_cast<const bf16x8*>(&QKV[voff]);
            bf16x8 vb = *reinterpret_cast<const bf16x8*>(&QKV[voff + 8]);
#pragma unroll
            for (int d = 0; d < 8; ++d) {
                acc[d]     = fmaf(e, bf2f((unsigned short)va[d]), acc[d]);
                acc[d + 8] = fmaf(e, bf2f((unsigned short)vb[d]), acc[d + 8]);
            }
        }
        mx = nm;
    }

    if (valid) {
        const float inv = 1.f / l;
        bf16x8 o0, o1;
#pragma unroll
        for (int t = 0; t < 8; ++t) {
            o0[t] = (short)f2bf(acc[t] * inv);
            o1[t] = (short)f2bf(acc[t + 8] * inv);
        }
        unsigned short* dst = &ctx[(size_t)(b * S_ + i) * H_ + h * HD_ + d0];
        *reinterpret_cast<bf16x8*>(dst) = o0;
        *reinterpret_cast<bf16x8*>(dst + 8) = o1;
    }
}

// ---------- launch ----------
extern "C" void kernel_launch(void* const* d_in, const int* in_sizes, int n_in,
                              void* d_out, int out_size, void* d_ws, size_t ws_size,
                              hipStream_t stream) {
    const float* feat  = (const float*)d_in[0];
    const float* pos   = (const float*)d_in[1];
    const float* Wq    = (const float*)d_in[2];
    const float* bq    = (const float*)d_in[3];
    const float* Wk    = (const float*)d_in[4];
    const float* bk    = (const float*)d_in[5];
    const float* Wv    = (const float*)d_in[6];
    const float* bv    = (const float*)d_in[7];
    const float* Wo    = (const float*)d_in[8];
    const float* bo    = (const float*)d_in[9];
    const float* ln_g  = (const float*)d_in[10];
    const float* ln_b  = (const float*)d_in[11];
    const int*   level = (const int*)d_in[12];
    float* out = (float*)d_out;

    char* ws = (char*)d_ws;
    unsigned short* xb   = (unsigned short*)ws;                      // [8000][768]
    unsigned short* Wcat = xb + (size_t)M_ * H_;                     // [3072][768] = Wq|Wk|Wv|Wo
    unsigned short* QKVb = Wcat + (size_t)4 * H_ * H_;               // [8000][2304]
    unsigned short* ctxb = QKVb + (size_t)M_ * HC_;                  // [8000][768]

    // 1) fused x-prep + weight cast
    const int nprep = (int)(((size_t)M_ * H_ / 4 + (size_t)4 * H_ * H_ / 4 + 255) / 256);
    prep_all_kernel<<<nprep, 256, 0, stream>>>(feat, pos, level, xb, Wq, Wk, Wv, Wo, Wcat);
    // 2) QKV = x @ [Wq|Wk|Wv]^T + bias   (grid 63x18 = 1134, 512 thr)
    gemm_qkv5<<<63 * 18, 512, 0, stream>>>(xb, Wcat, bq, bk, bv, QKVb);
    // 3) banded attention -> ctx (bf16)
    attn_kernel<<<B_ * NH_ * 16, 256, 0, stream>>>(QKVb, ctxb, level);
    // 4) y = LN(ctx @ Wo^T + bo + features)  (fused, grid 250, 512 thr)
    gemm_out_ln<<<250, 512, 0, stream>>>(ctxb, Wcat + (size_t)3 * H_ * H_, bo, feat,
                                         ln_g, ln_b, out);
}

// Round 12
// 112.853 us; speedup vs baseline: 3.0424x; 1.0406x over previous
//
#include <hip/hip_runtime.h>
#include <hip/hip_bf16.h>
#include <cstddef>

// ---------- types / helpers ----------
typedef __attribute__((ext_vector_type(8))) short bf16x8;
typedef __attribute__((ext_vector_type(4))) float f32x4;

static __device__ __forceinline__ unsigned short f2bf(float f) {
    unsigned int u = __float_as_uint(f);
    u += 0x7fffu + ((u >> 16) & 1u);
    return (unsigned short)(u >> 16);
}
static __device__ __forceinline__ float bf2f(unsigned short h) {
    return __uint_as_float(((unsigned int)h) << 16);
}

#define B_ 8
#define S_ 1000
#define H_ 768
#define NH_ 12
#define HD_ 64
#define M_ 8000
#define HC_ 2304   // 3*768

// ---------- kernel 1: fused (x = features + pos*scale -> bf16) + (weights -> bf16) ----------
__global__ __launch_bounds__(256)
void prep_all_kernel(const float* __restrict__ feat, const float* __restrict__ pos,
                     const int* __restrict__ level, unsigned short* __restrict__ xb,
                     const float* __restrict__ wq, const float* __restrict__ wk,
                     const float* __restrict__ wv, const float* __restrict__ wo,
                     unsigned short* __restrict__ wdst) {
    const size_t NX = (size_t)M_ * H_ / 4;
    const size_t WSZ = (size_t)H_ * H_;
    size_t gid = (size_t)blockIdx.x * blockDim.x + threadIdx.x;
    if (gid < NX) {
        size_t e = gid * 4;
        float sc = 1.0f + 0.1f * (float)level[0];
        const float4 f = *reinterpret_cast<const float4*>(&feat[e]);
        size_t pe = e % ((size_t)S_ * H_);
        const float4 p = *reinterpret_cast<const float4*>(&pos[pe]);
        ushort4 o;
        o.x = f2bf(f.x + sc * p.x);
        o.y = f2bf(f.y + sc * p.y);
        o.z = f2bf(f.z + sc * p.z);
        o.w = f2bf(f.w + sc * p.w);
        *reinterpret_cast<ushort4*>(&xb[e]) = o;
    } else {
        size_t e = (gid - NX) * 4;
        if (e >= 4 * WSZ) return;
        const float* src; size_t off;
        if (e < WSZ)          { src = wq; off = e; }
        else if (e < 2 * WSZ) { src = wk; off = e - WSZ; }
        else if (e < 3 * WSZ) { src = wv; off = e - 2 * WSZ; }
        else                  { src = wo; off = e - 3 * WSZ; }
        const float4 f = *reinterpret_cast<const float4*>(&src[off]);
        ushort4 o;
        o.x = f2bf(f.x); o.y = f2bf(f.y); o.z = f2bf(f.z); o.w = f2bf(f.w);
        *reinterpret_cast<ushort4*>(&wdst[e]) = o;
    }
}

// ---------- kernel 2: QKV GEMM, 128x256 tile, 8 waves (2x4), 64x64 wave-tile ----------
// Double-buffered BK=32 (2 x 24KB = 48KB -> 2 blocks/CU), counted vmcnt(3),
// 2-barrier pattern. __launch_bounds__(512,4): unified VGPR+AGPR cap 128 —
// acc 64 + operands fits, NO spill (R10's (512,6) cap 85 spilled).
// 64x64 wave-tile halves LDS bytes/MFMA vs 64x32 (512 vs 768 B) — LDS-BW
// is the measured wall. Swizzle: phys_slot = log ^ ((row>>1)&3), pre-applied
// on global source, linear gload_lds dest, same XOR on ds_read.
// Swapped-operand MFMA -> thread holds 4 consecutive cols -> ushort4 stores.
__global__ __launch_bounds__(512, 4)
void gemm_qkv6(const unsigned short* __restrict__ A,
               const unsigned short* __restrict__ Bw,
               const float* __restrict__ b0, const float* __restrict__ b1,
               const float* __restrict__ b2,
               unsigned short* __restrict__ outB) {
    const int K = H_;
    __shared__ char lds[49152];                       // 2 x 24KB buffers
    const int tid = threadIdx.x, lane = tid & 63, wid = tid >> 6;
    const int wr = wid >> 2, wc = wid & 3;            // 2 x 4 waves; per-wave 64x64
    const int fr = lane & 15, fq = lane >> 4;

    // bijective XCD swizzle (nwg = 567, not %8)
    const int nwg = gridDim.x;
    const int q = nwg >> 3, r = nwg & 7;
    const int xcd = blockIdx.x & 7, idx = blockIdx.x >> 3;
    const int swz = (xcd < r) ? (xcd * (q + 1) + idx) : (r * (q + 1) + (xcd - r) * q + idx);
    const int ntn = HC_ / 256;                        // 9
    const int bm = (swz / ntn) * 128;
    const int bn = (swz % ntn) * 256;

    const int srow = lane >> 2;
    const int scol = ((lane & 3) ^ ((lane >> 3) & 3)) * 8;   // pre-swizzled source k-offset

    auto stage = [&](int buf, int k0) {
        char* base = lds + buf * 24576;
        // A: 8 chunks of 16 rows; wave w stages chunk w
        int ar = bm + wid * 16 + srow;
        ar = ar < M_ ? ar : M_ - 1;                   // clamp: junk rows -> out-rows >= M (skipped)
        __builtin_amdgcn_global_load_lds(
            (const __attribute__((address_space(1))) unsigned int*)(A + (size_t)ar * K + k0 + scol),
            (__attribute__((address_space(3))) unsigned int*)(base + wid * 1024), 16, 0, 0);
        // B: 16 chunks; wave w stages chunks 2w, 2w+1 (HC_ multiple of 256)
#pragma unroll
        for (int t = 0; t < 2; ++t) {
            const int c = wid * 2 + t;
            const int br = bn + c * 16 + srow;
            __builtin_amdgcn_global_load_lds(
                (const __attribute__((address_space(1))) unsigned int*)(Bw + (size_t)br * K + k0 + scol),
                (__attribute__((address_space(3))) unsigned int*)(base + 8192 + c * 1024), 16, 0, 0);
        }
    };

    f32x4 acc[4][4] = {};
    const int rsl = fq ^ ((fr >> 1) & 3);
    const int NT = K / 32;                            // 24

    stage(0, 0);                                      // 3 loads/wave in flight
    for (int t = 0; t < NT; ++t) {
        const int cur = t & 1;
        if (t + 1 < NT) {
            stage(cur ^ 1, (t + 1) * 32);             // +3 -> 6 outstanding
            asm volatile("s_waitcnt vmcnt(3)" ::: "memory");   // oldest 3 (tile t) landed
        } else {
            asm volatile("s_waitcnt vmcnt(0)" ::: "memory");
        }
        __builtin_amdgcn_s_barrier();                 // tile t visible to all waves

        char* base = lds + cur * 24576;
        bf16x8 af[4], bfv[4];
#pragma unroll
        for (int m = 0; m < 4; ++m) {
            const int row = wr * 64 + m * 16 + fr;
            af[m] = *reinterpret_cast<const bf16x8*>(base + row * 64 + rsl * 16);
        }
#pragma unroll
        for (int n = 0; n < 4; ++n) {
            const int row = wc * 64 + n * 16 + fr;
            bfv[n] = *reinterpret_cast<const bf16x8*>(base + 8192 + row * 64 + rsl * 16);
        }
        __builtin_amdgcn_s_setprio(1);
#pragma unroll
        for (int m = 0; m < 4; ++m)
#pragma unroll
            for (int n = 0; n < 4; ++n)
                acc[m][n] = __builtin_amdgcn_mfma_f32_16x16x32_bf16(bfv[n], af[m], acc[m][n], 0, 0, 0);
        __builtin_amdgcn_s_setprio(0);
        __builtin_amdgcn_s_barrier();                 // reads done before buffer reuse
    }

    // epilogue: row = bm + wr*64 + m*16 + fr, col = bn + wc*64 + n*16 + fq*4 + j
    const int colg = (bn < 768) ? bn : (bn < 1536) ? bn - 768 : bn - 1536;
    const float* bsel = (bn < 768) ? b0 : (bn < 1536) ? b1 : b2;
#pragma unroll
    for (int m = 0; m < 4; ++m) {
        const int row = bm + wr * 64 + m * 16 + fr;
        if (row >= M_) continue;
#pragma unroll
        for (int n = 0; n < 4; ++n) {
            const int cb = wc * 64 + n * 16 + fq * 4;
            const float4 bv = *reinterpret_cast<const float4*>(&bsel[colg + cb]);
            ushort4 o;
            o.x = f2bf(acc[m][n][0] + bv.x);
            o.y = f2bf(acc[m][n][1] + bv.y);
            o.z = f2bf(acc[m][n][2] + bv.z);
            o.w = f2bf(acc[m][n][3] + bv.w);
            *reinterpret_cast<ushort4*>(&outB[(size_t)row * HC_ + bn + cb]) = o;
        }
    }
}

// ---------- kernel 4: out-proj GEMM, 128x64 tile, 4 waves (2x2), 64x32 wave-tile ----------
// (R7 proven) y = ctx @ Wo^T + bo + resid, fp32 out. BK=32 dbuf, vmcnt(3).
__global__ __launch_bounds__(256, 4)
void gemm_out2(const unsigned short* __restrict__ A,   // [8000][768] ctx
               const unsigned short* __restrict__ Bw,  // [768][768] Wo
               const float* __restrict__ b0,
               const float* __restrict__ resid,
               float* __restrict__ outF) {
    const int K = H_;
    __shared__ char lds[24576];                        // dbuf x (A 8KB + B 4KB)
    const int tid = threadIdx.x, lane = tid & 63, wid = tid >> 6;
    const int wr = wid >> 1, wc = wid & 1;             // 2 x 2 waves; per-wave 64x32
    const int fr = lane & 15, fq = lane >> 4;

    const int nwg = gridDim.x;
    const int q = nwg >> 3, r = nwg & 7;
    const int xcd = blockIdx.x & 7, idx = blockIdx.x >> 3;
    const int swz = (xcd < r) ? (xcd * (q + 1) + idx) : (r * (q + 1) + (xcd - r) * q + idx);
    const int ntn = H_ / 64;
    const int bm = (swz / ntn) * 128;
    const int bn = (swz % ntn) * 64;

    const int srow = lane >> 2;
    const int scol = ((lane & 3) ^ ((lane >> 3) & 3)) * 8;

    auto stage = [&](int buf, int k0) {
        char* base = lds + buf * 12288;
#pragma unroll
        for (int t = 0; t < 2; ++t) {
            const int c = wid * 2 + t;                 // A: 8 chunks of 16 rows
            int ar = bm + c * 16 + srow;
            ar = ar < M_ ? ar : M_ - 1;
            __builtin_amdgcn_global_load_lds(
                (const __attribute__((address_space(1))) unsigned int*)(A + (size_t)ar * K + k0 + scol),
                (__attribute__((address_space(3))) unsigned int*)(base + c * 1024), 16, 0, 0);
        }
        const int c = wid;                             // B: 4 chunks
        const int br = bn + c * 16 + srow;             // H_ multiple of 64
        __builtin_amdgcn_global_load_lds(
            (const __attribute__((address_space(1))) unsigned int*)(Bw + (size_t)br * K + k0 + scol),
            (__attribute__((address_space(3))) unsigned int*)(base + 8192 + c * 1024), 16, 0, 0);
    };

    f32x4 acc[4][2] = {};
    const int rsl = fq ^ ((fr >> 1) & 3);
    const int NT = K / 32;

    stage(0, 0);
    for (int t = 0; t < NT; ++t) {
        const int cur = t & 1;
        if (t + 1 < NT) {
            stage(cur ^ 1, (t + 1) * 32);
            asm volatile("s_waitcnt vmcnt(3)" ::: "memory");
        } else {
            asm volatile("s_waitcnt vmcnt(0)" ::: "memory");
        }
        __builtin_amdgcn_s_barrier();

        char* base = lds + cur * 12288;
        bf16x8 af[4], bfv[2];
#pragma unroll
        for (int m = 0; m < 4; ++m) {
            const int row = wr * 64 + m * 16 + fr;
            af[m] = *reinterpret_cast<const bf16x8*>(base + row * 64 + rsl * 16);
        }
#pragma unroll
        for (int n = 0; n < 2; ++n) {
            const int row = wc * 32 + n * 16 + fr;
            bfv[n] = *reinterpret_cast<const bf16x8*>(base + 8192 + row * 64 + rsl * 16);
        }
        __builtin_amdgcn_s_setprio(1);
#pragma unroll
        for (int m = 0; m < 4; ++m)
#pragma unroll
            for (int n = 0; n < 2; ++n)
                acc[m][n] = __builtin_amdgcn_mfma_f32_16x16x32_bf16(bfv[n], af[m], acc[m][n], 0, 0, 0);
        __builtin_amdgcn_s_setprio(0);
        __builtin_amdgcn_s_barrier();
    }

    // epilogue: row fixed per thread, 4 consecutive cols -> float4 ops
#pragma unroll
    for (int m = 0; m < 4; ++m) {
        const int row = bm + wr * 64 + m * 16 + fr;
        if (row >= M_) continue;
#pragma unroll
        for (int n = 0; n < 2; ++n) {
            const int col = bn + wc * 32 + n * 16 + fq * 4;
            const float4 bv = *reinterpret_cast<const float4*>(&b0[col]);
            const float4 rv = *reinterpret_cast<const float4*>(&resid[(size_t)row * H_ + col]);
            float4 ov;
            ov.x = acc[m][n][0] + bv.x + rv.x;
            ov.y = acc[m][n][1] + bv.y + rv.y;
            ov.z = acc[m][n][2] + bv.z + rv.z;
            ov.w = acc[m][n][3] + bv.w + rv.w;
            *reinterpret_cast<float4*>(&outF[(size_t)row * H_ + col]) = ov;
        }
    }
}

// ---------- kernel 3: banded attention, 16 queries/wave, 4 lanes x 16 dims ----------
__global__ __launch_bounds__(256)
void attn_kernel(const unsigned short* __restrict__ QKV,
                 unsigned short* __restrict__ ctx,
                 const int* __restrict__ level_p) {
    const int lane = threadIdx.x & 63;
    const int wv = threadIdx.x >> 6;
    const int qiw = lane >> 2;
    const int d0 = (lane & 3) * 16;

    const int qt = blockIdx.x & 15;
    const int h  = (blockIdx.x >> 4) % NH_;
    const int b  = blockIdx.x / (16 * NH_);
    const int i  = qt * 64 + wv * 16 + qiw;
    const bool valid = i < S_;
    const int iq = valid ? i : S_ - 1;

    const int lev = level_p[0];
    const int w = (lev == 0) ? 2 : (lev == 1) ? 5 : S_;

    const size_t qoff = (size_t)(b * S_ + iq) * HC_ + h * HD_ + d0;
    bf16x8 qa = *reinterpret_cast<const bf16x8*>(&QKV[qoff]);
    bf16x8 qb = *reinterpret_cast<const bf16x8*>(&QKV[qoff + 8]);
    float qf[16];
#pragma unroll
    for (int t = 0; t < 8; ++t) {
        qf[t]     = bf2f((unsigned short)qa[t]);
        qf[t + 8] = bf2f((unsigned short)qb[t]);
    }

    const int j0 = max(0, i - w), j1 = min(S_ - 1, i + w);
    float mx = -1e30f, l = 0.f;
    float acc[16];
#pragma unroll
    for (int t = 0; t < 16; ++t) acc[t] = 0.f;

    for (int jc = j0; jc <= j1; jc += 5) {
        float s[5];
        int jj[5];
#pragma unroll
        for (int t = 0; t < 5; ++t) {
            const int j = jc + t;
            jj[t] = j <= j1 ? j : j1;
            const size_t koff = (size_t)(b * S_ + jj[t]) * HC_ + 768 + h * HD_ + d0;
            bf16x8 ka = *reinterpret_cast<const bf16x8*>(&QKV[koff]);
            bf16x8 kb = *reinterpret_cast<const bf16x8*>(&QKV[koff + 8]);
            float p = 0.f;
#pragma unroll
            for (int d = 0; d < 8; ++d) {
                p = fmaf(qf[d], bf2f((unsigned short)ka[d]), p);
                p = fmaf(qf[d + 8], bf2f((unsigned short)kb[d]), p);
            }
            s[t] = p;
        }
#pragma unroll
        for (int t = 0; t < 5; ++t) s[t] += __shfl_xor(s[t], 1);
#pragma unroll
        for (int t = 0; t < 5; ++t) s[t] += __shfl_xor(s[t], 2);
#pragma unroll
        for (int t = 0; t < 5; ++t)
            s[t] = (jc + t <= j1) ? s[t] * 0.125f : -1e30f;

        float cm = fmaxf(fmaxf(fmaxf(s[0], s[1]), fmaxf(s[2], s[3])), s[4]);
        float nm = fmaxf(mx, cm);
        float corr = __expf(mx - nm);
        l *= corr;
#pragma unroll
        for (int t = 0; t < 16; ++t) acc[t] *= corr;
#pragma unroll
        for (int t = 0; t < 5; ++t) {
            const float e = __expf(s[t] - nm);
            l += e;
            const size_t voff = (size_t)(b * S_ + jj[t]) * HC_ + 1536 + h * HD_ + d0;
            bf16x8 va = *reinterpret_cast<const bf16x8*>(&QKV[voff]);
            bf16x8 vb = *reinterpret_cast<const bf16x8*>(&QKV[voff + 8]);
#pragma unroll
            for (int d = 0; d < 8; ++d) {
                acc[d]     = fmaf(e, bf2f((unsigned short)va[d]), acc[d]);
                acc[d + 8] = fmaf(e, bf2f((unsigned short)vb[d]), acc[d + 8]);
            }
        }
        mx = nm;
    }

    if (valid) {
        const float inv = 1.f / l;
        bf16x8 o0, o1;
#pragma unroll
        for (int t = 0; t < 8; ++t) {
            o0[t] = (short)f2bf(acc[t] * inv);
            o1[t] = (short)f2bf(acc[t + 8] * inv);
        }
        unsigned short* dst = &ctx[(size_t)(b * S_ + i) * H_ + h * HD_ + d0];
        *reinterpret_cast<bf16x8*>(dst) = o0;
        *reinterpret_cast<bf16x8*>(dst + 8) = o1;
    }
}

// ---------- kernel 5: in-place LayerNorm over rows of d_out ----------
__global__ __launch_bounds__(256)
void ln_kernel(float* __restrict__ y, const float* __restrict__ g, const float* __restrict__ bta) {
    int row = blockIdx.x;
    int tid = threadIdx.x;
    float* p = y + (size_t)row * H_;
    float v[3];
    float s = 0.f, s2 = 0.f;
#pragma unroll
    for (int t = 0; t < 3; ++t) {
        v[t] = p[tid + t * 256];
        s += v[t];
        s2 += v[t] * v[t];
    }
#pragma unroll
    for (int o = 32; o; o >>= 1) {
        s  += __shfl_xor(s, o);
        s2 += __shfl_xor(s2, o);
    }
    __shared__ float ss[4], ss2[4];
    if ((tid & 63) == 0) { ss[tid >> 6] = s; ss2[tid >> 6] = s2; }
    __syncthreads();
    s  = ss[0] + ss[1] + ss[2] + ss[3];
    s2 = ss2[0] + ss2[1] + ss2[2] + ss2[3];
    float mu = s * (1.f / H_);
    float var = s2 * (1.f / H_) - mu * mu;
    float rs = rsqrtf(var + 1e-5f);
#pragma unroll
    for (int t = 0; t < 3; ++t) {
        int c = tid + t * 256;
        p[c] = (v[t] - mu) * rs * g[c] + bta[c];
    }
}

// ---------- launch ----------
extern "C" void kernel_launch(void* const* d_in, const int* in_sizes, int n_in,
                              void* d_out, int out_size, void* d_ws, size_t ws_size,
                              hipStream_t stream) {
    const float* feat  = (const float*)d_in[0];
    const float* pos   = (const float*)d_in[1];
    const float* Wq    = (const float*)d_in[2];
    const float* bq    = (const float*)d_in[3];
    const float* Wk    = (const float*)d_in[4];
    const float* bk    = (const float*)d_in[5];
    const float* Wv    = (const float*)d_in[6];
    const float* bv    = (const float*)d_in[7];
    const float* Wo    = (const float*)d_in[8];
    const float* bo    = (const float*)d_in[9];
    const float* ln_g  = (const float*)d_in[10];
    const float* ln_b  = (const float*)d_in[11];
    const int*   level = (const int*)d_in[12];
    float* out = (float*)d_out;

    char* ws = (char*)d_ws;
    unsigned short* xb   = (unsigned short*)ws;                      // [8000][768]
    unsigned short* Wcat = xb + (size_t)M_ * H_;                     // [3072][768] = Wq|Wk|Wv|Wo
    unsigned short* QKVb = Wcat + (size_t)4 * H_ * H_;               // [8000][2304]
    unsigned short* ctxb = QKVb + (size_t)M_ * HC_;                  // [8000][768]

    // 1) fused x-prep + weight cast
    const int nprep = (int)(((size_t)M_ * H_ / 4 + (size_t)4 * H_ * H_ / 4 + 255) / 256);
    prep_all_kernel<<<nprep, 256, 0, stream>>>(feat, pos, level, xb, Wq, Wk, Wv, Wo, Wcat);
    // 2) QKV = x @ [Wq|Wk|Wv]^T + bias   (grid 63x9 = 567, 512 thr, 2 blk/CU)
    gemm_qkv6<<<63 * 9, 512, 0, stream>>>(xb, Wcat, bq, bk, bv, QKVb);
    // 3) banded attention -> ctx (bf16)
    attn_kernel<<<B_ * NH_ * 16, 256, 0, stream>>>(QKVb, ctxb, level);
    // 4) y = ctx @ Wo^T + bo + features  (grid 63x12 = 756, 256 thr)
    gemm_out2<<<63 * 12, 256, 0, stream>>>(ctxb, Wcat + (size_t)3 * H_ * H_, bo, feat, out);
    // 5) LayerNorm in place on d_out
    ln_kernel<<<M_, 256, 0, stream>>>(out, ln_g, ln_b);
}

// Round 13
// 106.689 us; speedup vs baseline: 3.2182x; 1.0578x over previous
//
#include <hip/hip_runtime.h>
#include <hip/hip_bf16.h>
#include <cstddef>

// ---------- types / helpers ----------
typedef __attribute__((ext_vector_type(8))) short bf16x8;
typedef __attribute__((ext_vector_type(4))) float f32x4;

static __device__ __forceinline__ unsigned short f2bf(float f) {
    unsigned int u = __float_as_uint(f);
    u += 0x7fffu + ((u >> 16) & 1u);
    return (unsigned short)(u >> 16);
}
static __device__ __forceinline__ float bf2f(unsigned short h) {
    return __uint_as_float(((unsigned int)h) << 16);
}

#define B_ 8
#define S_ 1000
#define H_ 768
#define NH_ 12
#define HD_ 64
#define M_ 8000
#define HC_ 2304   // 3*768

// ---------- kernel 1: fused (x = features + pos*scale -> bf16) + (weights -> bf16) ----------
__global__ __launch_bounds__(256)
void prep_all_kernel(const float* __restrict__ feat, const float* __restrict__ pos,
                     const int* __restrict__ level, unsigned short* __restrict__ xb,
                     const float* __restrict__ wq, const float* __restrict__ wk,
                     const float* __restrict__ wv, const float* __restrict__ wo,
                     unsigned short* __restrict__ wdst) {
    const size_t NX = (size_t)M_ * H_ / 4;
    const size_t WSZ = (size_t)H_ * H_;
    size_t gid = (size_t)blockIdx.x * blockDim.x + threadIdx.x;
    if (gid < NX) {
        size_t e = gid * 4;
        float sc = 1.0f + 0.1f * (float)level[0];
        const float4 f = *reinterpret_cast<const float4*>(&feat[e]);
        size_t pe = e % ((size_t)S_ * H_);
        const float4 p = *reinterpret_cast<const float4*>(&pos[pe]);
        ushort4 o;
        o.x = f2bf(f.x + sc * p.x);
        o.y = f2bf(f.y + sc * p.y);
        o.z = f2bf(f.z + sc * p.z);
        o.w = f2bf(f.w + sc * p.w);
        *reinterpret_cast<ushort4*>(&xb[e]) = o;
    } else {
        size_t e = (gid - NX) * 4;
        if (e >= 4 * WSZ) return;
        const float* src; size_t off;
        if (e < WSZ)          { src = wq; off = e; }
        else if (e < 2 * WSZ) { src = wk; off = e - WSZ; }
        else if (e < 3 * WSZ) { src = wv; off = e - 2 * WSZ; }
        else                  { src = wo; off = e - 3 * WSZ; }
        const float4 f = *reinterpret_cast<const float4*>(&src[off]);
        ushort4 o;
        o.x = f2bf(f.x); o.y = f2bf(f.y); o.z = f2bf(f.z); o.w = f2bf(f.w);
        *reinterpret_cast<ushort4*>(&wdst[e]) = o;
    }
}

// ---------- kernel 2: QKV GEMM (R11 proven, 49.4us), 128x128 tile, 8 waves, 64x32/wave ----------
// BK=64 per barrier-pair: each 32KB buffer = two 16KB sub-tiles (swizzled
// [128rows][32k] 64B-row layout). Double-buffered, counted vmcnt(4), 12
// barrier-pairs. bounds(512,4). Swizzle: phys_slot = log ^ ((row>>1)&3)
// pre-applied on global source; linear gload_lds dest; same XOR on ds_read.
// Swapped-operand MFMA -> thread holds 4 consecutive cols -> ushort4 stores.
__global__ __launch_bounds__(512, 4)
void gemm_qkv5(const unsigned short* __restrict__ A,
               const unsigned short* __restrict__ Bw,
               const float* __restrict__ b0, const float* __restrict__ b1,
               const float* __restrict__ b2,
               unsigned short* __restrict__ outB) {
    const int K = H_;
    __shared__ char lds[65536];                       // 2 buffers x 2 sub-tiles x 16KB
    const int tid = threadIdx.x, lane = tid & 63, wid = tid >> 6;
    const int wr = wid >> 2, wc = wid & 3;            // 2 x 4 waves; per-wave 64x32
    const int fr = lane & 15, fq = lane >> 4;

    // bijective XCD swizzle (nwg = 1134, not %8)
    const int nwg = gridDim.x;
    const int q = nwg >> 3, r = nwg & 7;
    const int xcd = blockIdx.x & 7, idx = blockIdx.x >> 3;
    const int swz = (xcd < r) ? (xcd * (q + 1) + idx) : (r * (q + 1) + (xcd - r) * q + idx);
    const int ntn = HC_ / 128;                        // 18
    const int bm = (swz / ntn) * 128;
    const int bn = (swz % ntn) * 128;

    const int srow = lane >> 2;
    const int scol = ((lane & 3) ^ ((lane >> 3) & 3)) * 8;   // pre-swizzled source k-offset

    // stage one BK=64 tile = 2 sub-tiles; 4 loads/wave
    auto stage = [&](int buf, int k0) {
        char* base = lds + buf * 32768;
#pragma unroll
        for (int s = 0; s < 2; ++s) {
            char* half = base + s * 16384;
            const int kk = k0 + s * 32;
            int ar = bm + wid * 16 + srow;            // 8 chunks of 16 rows; wave w -> chunk w
            ar = ar < M_ ? ar : M_ - 1;               // clamp: junk rows -> out-rows >= M (skipped)
            __builtin_amdgcn_global_load_lds(
                (const __attribute__((address_space(1))) unsigned int*)(A + (size_t)ar * K + kk + scol),
                (__attribute__((address_space(3))) unsigned int*)(half + wid * 1024), 16, 0, 0);
            const int br = bn + wid * 16 + srow;      // HC_ multiple of 128
            __builtin_amdgcn_global_load_lds(
                (const __attribute__((address_space(1))) unsigned int*)(Bw + (size_t)br * K + kk + scol),
                (__attribute__((address_space(3))) unsigned int*)(half + 8192 + wid * 1024), 16, 0, 0);
        }
    };

    f32x4 acc[4][2] = {};
    const int rsl = fq ^ ((fr >> 1) & 3);
    const int NT = K / 64;                            // 12

    stage(0, 0);                                      // 4 loads/wave in flight
    for (int t = 0; t < NT; ++t) {
        const int cur = t & 1;
        if (t + 1 < NT) {
            stage(cur ^ 1, (t + 1) * 64);             // +4 -> 8 outstanding
            asm volatile("s_waitcnt vmcnt(4)" ::: "memory");   // oldest 4 (tile t) landed
        } else {
            asm volatile("s_waitcnt vmcnt(0)" ::: "memory");
        }
        __builtin_amdgcn_s_barrier();                 // tile t visible to all waves

        char* base = lds + cur * 32768;
#pragma unroll
        for (int s = 0; s < 2; ++s) {                 // two 32-k sub-steps per barrier-pair
            char* half = base + s * 16384;
            bf16x8 af[4], bfv[2];
#pragma unroll
            for (int m = 0; m < 4; ++m) {
                const int row = wr * 64 + m * 16 + fr;
                af[m] = *reinterpret_cast<const bf16x8*>(half + row * 64 + rsl * 16);
            }
#pragma unroll
            for (int n = 0; n < 2; ++n) {
                const int row = wc * 32 + n * 16 + fr;
                bfv[n] = *reinterpret_cast<const bf16x8*>(half + 8192 + row * 64 + rsl * 16);
            }
            __builtin_amdgcn_s_setprio(1);
#pragma unroll
            for (int m = 0; m < 4; ++m)
#pragma unroll
                for (int n = 0; n < 2; ++n)
                    acc[m][n] = __builtin_amdgcn_mfma_f32_16x16x32_bf16(bfv[n], af[m], acc[m][n], 0, 0, 0);
            __builtin_amdgcn_s_setprio(0);
        }
        __builtin_amdgcn_s_barrier();                 // reads done before buffer reuse
    }

    // epilogue: row = bm + wr*64 + m*16 + fr (thread-fixed), col = bn + wc*32 + n*16 + fq*4 + j
    const int colg = (bn < 768) ? bn : (bn < 1536) ? bn - 768 : bn - 1536;
    const float* bsel = (bn < 768) ? b0 : (bn < 1536) ? b1 : b2;
#pragma unroll
    for (int m = 0; m < 4; ++m) {
        const int row = bm + wr * 64 + m * 16 + fr;
        if (row >= M_) continue;
#pragma unroll
        for (int n = 0; n < 2; ++n) {
            const int cb = wc * 32 + n * 16 + fq * 4;
            const float4 bv = *reinterpret_cast<const float4*>(&bsel[colg + cb]);
            ushort4 o;
            o.x = f2bf(acc[m][n][0] + bv.x);
            o.y = f2bf(acc[m][n][1] + bv.y);
            o.z = f2bf(acc[m][n][2] + bv.z);
            o.w = f2bf(acc[m][n][3] + bv.w);
            *reinterpret_cast<ushort4*>(&outB[(size_t)row * HC_ + bn + cb]) = o;
        }
    }
}

// ---------- kernel 4: out-proj GEMM, 128x64 tile, 4 waves (2x2), 64x32 wave-tile ----------
// y = ctx @ Wo^T + bo + resid, fp32 out. BK=64 per barrier-pair (two 12KB
// sub-tiles/buffer, 48KB dbuf -> 3 blocks/CU; grid 756 <= capacity 768 ->
// single generation). Uniform 6 loads/wave/tile -> counted vmcnt(6).
__global__ __launch_bounds__(256, 4)
void gemm_out4(const unsigned short* __restrict__ A,   // [8000][768] ctx
               const unsigned short* __restrict__ Bw,  // [768][768] Wo
               const float* __restrict__ b0,
               const float* __restrict__ resid,
               float* __restrict__ outF) {
    const int K = H_;
    __shared__ char lds[49152];                        // 2 buffers x 2 sub-tiles x 12KB
    const int tid = threadIdx.x, lane = tid & 63, wid = tid >> 6;
    const int wr = wid >> 1, wc = wid & 1;             // 2 x 2 waves; per-wave 64x32
    const int fr = lane & 15, fq = lane >> 4;

    const int nwg = gridDim.x;                         // 756
    const int q = nwg >> 3, r = nwg & 7;
    const int xcd = blockIdx.x & 7, idx = blockIdx.x >> 3;
    const int swz = (xcd < r) ? (xcd * (q + 1) + idx) : (r * (q + 1) + (xcd - r) * q + idx);
    const int ntn = H_ / 64;
    const int bm = (swz / ntn) * 128;
    const int bn = (swz % ntn) * 64;

    const int srow = lane >> 2;
    const int scol = ((lane & 3) ^ ((lane >> 3) & 3)) * 8;

    // stage one BK=64 tile = 2 sub-tiles; per sub-tile: A 8 chunks (2/wave),
    // B 4 chunks (1/wave) -> 6 loads/wave/tile, uniform
    auto stage = [&](int buf, int k0) {
        char* base = lds + buf * 24576;
#pragma unroll
        for (int s = 0; s < 2; ++s) {
            char* half = base + s * 12288;
            const int kk = k0 + s * 32;
#pragma unroll
            for (int t = 0; t < 2; ++t) {
                const int c = wid * 2 + t;             // A chunks 0..7
                int ar = bm + c * 16 + srow;
                ar = ar < M_ ? ar : M_ - 1;
                __builtin_amdgcn_global_load_lds(
                    (const __attribute__((address_space(1))) unsigned int*)(A + (size_t)ar * K + kk + scol),
                    (__attribute__((address_space(3))) unsigned int*)(half + c * 1024), 16, 0, 0);
            }
            const int br = bn + wid * 16 + srow;       // B chunks 0..3 (H_ mult of 64)
            __builtin_amdgcn_global_load_lds(
                (const __attribute__((address_space(1))) unsigned int*)(Bw + (size_t)br * K + kk + scol),
                (__attribute__((address_space(3))) unsigned int*)(half + 8192 + wid * 1024), 16, 0, 0);
        }
    };

    f32x4 acc[4][2] = {};
    const int rsl = fq ^ ((fr >> 1) & 3);
    const int NT = K / 64;                             // 12

    stage(0, 0);                                       // 6 loads/wave
    for (int t = 0; t < NT; ++t) {
        const int cur = t & 1;
        if (t + 1 < NT) {
            stage(cur ^ 1, (t + 1) * 64);              // +6 -> 12 outstanding
            asm volatile("s_waitcnt vmcnt(6)" ::: "memory");   // oldest 6 (tile t) landed
        } else {
            asm volatile("s_waitcnt vmcnt(0)" ::: "memory");
        }
        __builtin_amdgcn_s_barrier();

        char* base = lds + cur * 24576;
#pragma unroll
        for (int s = 0; s < 2; ++s) {
            char* half = base + s * 12288;
            bf16x8 af[4], bfv[2];
#pragma unroll
            for (int m = 0; m < 4; ++m) {
                const int row = wr * 64 + m * 16 + fr;
                af[m] = *reinterpret_cast<const bf16x8*>(half + row * 64 + rsl * 16);
            }
#pragma unroll
            for (int n = 0; n < 2; ++n) {
                const int row = wc * 32 + n * 16 + fr;
                bfv[n] = *reinterpret_cast<const bf16x8*>(half + 8192 + row * 64 + rsl * 16);
            }
            __builtin_amdgcn_s_setprio(1);
#pragma unroll
            for (int m = 0; m < 4; ++m)
#pragma unroll
                for (int n = 0; n < 2; ++n)
                    acc[m][n] = __builtin_amdgcn_mfma_f32_16x16x32_bf16(bfv[n], af[m], acc[m][n], 0, 0, 0);
            __builtin_amdgcn_s_setprio(0);
        }
        __builtin_amdgcn_s_barrier();
    }

    // epilogue: row fixed per thread, 4 consecutive cols -> float4 ops
#pragma unroll
    for (int m = 0; m < 4; ++m) {
        const int row = bm + wr * 64 + m * 16 + fr;
        if (row >= M_) continue;
#pragma unroll
        for (int n = 0; n < 2; ++n) {
            const int col = bn + wc * 32 + n * 16 + fq * 4;
            const float4 bv = *reinterpret_cast<const float4*>(&b0[col]);
            const float4 rv = *reinterpret_cast<const float4*>(&resid[(size_t)row * H_ + col]);
            float4 ov;
            ov.x = acc[m][n][0] + bv.x + rv.x;
            ov.y = acc[m][n][1] + bv.y + rv.y;
            ov.z = acc[m][n][2] + bv.z + rv.z;
            ov.w = acc[m][n][3] + bv.w + rv.w;
            *reinterpret_cast<float4*>(&outF[(size_t)row * H_ + col]) = ov;
        }
    }
}

// ---------- kernel 3: banded attention, 16 queries/wave, 4 lanes x 16 dims ----------
__global__ __launch_bounds__(256)
void attn_kernel(const unsigned short* __restrict__ QKV,
                 unsigned short* __restrict__ ctx,
                 const int* __restrict__ level_p) {
    const int lane = threadIdx.x & 63;
    const int wv = threadIdx.x >> 6;
    const int qiw = lane >> 2;
    const int d0 = (lane & 3) * 16;

    const int qt = blockIdx.x & 15;
    const int h  = (blockIdx.x >> 4) % NH_;
    const int b  = blockIdx.x / (16 * NH_);
    const int i  = qt * 64 + wv * 16 + qiw;
    const bool valid = i < S_;
    const int iq = valid ? i : S_ - 1;

    const int lev = level_p[0];
    const int w = (lev == 0) ? 2 : (lev == 1) ? 5 : S_;

    const size_t qoff = (size_t)(b * S_ + iq) * HC_ + h * HD_ + d0;
    bf16x8 qa = *reinterpret_cast<const bf16x8*>(&QKV[qoff]);
    bf16x8 qb = *reinterpret_cast<const bf16x8*>(&QKV[qoff + 8]);
    float qf[16];
#pragma unroll
    for (int t = 0; t < 8; ++t) {
        qf[t]     = bf2f((unsigned short)qa[t]);
        qf[t + 8] = bf2f((unsigned short)qb[t]);
    }

    const int j0 = max(0, i - w), j1 = min(S_ - 1, i + w);
    float mx = -1e30f, l = 0.f;
    float acc[16];
#pragma unroll
    for (int t = 0; t < 16; ++t) acc[t] = 0.f;

    for (int jc = j0; jc <= j1; jc += 5) {
        float s[5];
        int jj[5];
#pragma unroll
        for (int t = 0; t < 5; ++t) {
            const int j = jc + t;
            jj[t] = j <= j1 ? j : j1;
            const size_t koff = (size_t)(b * S_ + jj[t]) * HC_ + 768 + h * HD_ + d0;
            bf16x8 ka = *reinterpret_cast<const bf16x8*>(&QKV[koff]);
            bf16x8 kb = *reinterpret_cast<const bf16x8*>(&QKV[koff + 8]);
            float p = 0.f;
#pragma unroll
            for (int d = 0; d < 8; ++d) {
                p = fmaf(qf[d], bf2f((unsigned short)ka[d]), p);
                p = fmaf(qf[d + 8], bf2f((unsigned short)kb[d]), p);
            }
            s[t] = p;
        }
#pragma unroll
        for (int t = 0; t < 5; ++t) s[t] += __shfl_xor(s[t], 1);
#pragma unroll
        for (int t = 0; t < 5; ++t) s[t] += __shfl_xor(s[t], 2);
#pragma unroll
        for (int t = 0; t < 5; ++t)
            s[t] = (jc + t <= j1) ? s[t] * 0.125f : -1e30f;

        float cm = fmaxf(fmaxf(fmaxf(s[0], s[1]), fmaxf(s[2], s[3])), s[4]);
        float nm = fmaxf(mx, cm);
        float corr = __expf(mx - nm);
        l *= corr;
#pragma unroll
        for (int t = 0; t < 16; ++t) acc[t] *= corr;
#pragma unroll
        for (int t = 0; t < 5; ++t) {
            const float e = __expf(s[t] - nm);
            l += e;
            const size_t voff = (size_t)(b * S_ + jj[t]) * HC_ + 1536 + h * HD_ + d0;
            bf16x8 va = *reinterpret_cast<const bf16x8*>(&QKV[voff]);
            bf16x8 vb = *reinterpret_cast<const bf16x8*>(&QKV[voff + 8]);
#pragma unroll
            for (int d = 0; d < 8; ++d) {
                acc[d]     = fmaf(e, bf2f((unsigned short)va[d]), acc[d]);
                acc[d + 8] = fmaf(e, bf2f((unsigned short)vb[d]), acc[d + 8]);
            }
        }
        mx = nm;
    }

    if (valid) {
        const float inv = 1.f / l;
        bf16x8 o0, o1;
#pragma unroll
        for (int t = 0; t < 8; ++t) {
            o0[t] = (short)f2bf(acc[t] * inv);
            o1[t] = (short)f2bf(acc[t + 8] * inv);
        }
        unsigned short* dst = &ctx[(size_t)(b * S_ + i) * H_ + h * HD_ + d0];
        *reinterpret_cast<bf16x8*>(dst) = o0;
        *reinterpret_cast<bf16x8*>(dst + 8) = o1;
    }
}

// ---------- kernel 5: in-place LayerNorm over rows of d_out ----------
__global__ __launch_bounds__(256)
void ln_kernel(float* __restrict__ y, const float* __restrict__ g, const float* __restrict__ bta) {
    int row = blockIdx.x;
    int tid = threadIdx.x;
    float* p = y + (size_t)row * H_;
    float v[3];
    float s = 0.f, s2 = 0.f;
#pragma unroll
    for (int t = 0; t < 3; ++t) {
        v[t] = p[tid + t * 256];
        s += v[t];
        s2 += v[t] * v[t];
    }
#pragma unroll
    for (int o = 32; o; o >>= 1) {
        s  += __shfl_xor(s, o);
        s2 += __shfl_xor(s2, o);
    }
    __shared__ float ss[4], ss2[4];
    if ((tid & 63) == 0) { ss[tid >> 6] = s; ss2[tid >> 6] = s2; }
    __syncthreads();
    s  = ss[0] + ss[1] + ss[2] + ss[3];
    s2 = ss2[0] + ss2[1] + ss2[2] + ss2[3];
    float mu = s * (1.f / H_);
    float var = s2 * (1.f / H_) - mu * mu;
    float rs = rsqrtf(var + 1e-5f);
#pragma unroll
    for (int t = 0; t < 3; ++t) {
        int c = tid + t * 256;
        p[c] = (v[t] - mu) * rs * g[c] + bta[c];
    }
}

// ---------- launch ----------
extern "C" void kernel_launch(void* const* d_in, const int* in_sizes, int n_in,
                              void* d_out, int out_size, void* d_ws, size_t ws_size,
                              hipStream_t stream) {
    const float* feat  = (const float*)d_in[0];
    const float* pos   = (const float*)d_in[1];
    const float* Wq    = (const float*)d_in[2];
    const float* bq    = (const float*)d_in[3];
    const float* Wk    = (const float*)d_in[4];
    const float* bk    = (const float*)d_in[5];
    const float* Wv    = (const float*)d_in[6];
    const float* bv    = (const float*)d_in[7];
    const float* Wo    = (const float*)d_in[8];
    const float* bo    = (const float*)d_in[9];
    const float* ln_g  = (const float*)d_in[10];
    const float* ln_b  = (const float*)d_in[11];
    const int*   level = (const int*)d_in[12];
    float* out = (float*)d_out;

    char* ws = (char*)d_ws;
    unsigned short* xb   = (unsigned short*)ws;                      // [8000][768]
    unsigned short* Wcat = xb + (size_t)M_ * H_;                     // [3072][768] = Wq|Wk|Wv|Wo
    unsigned short* QKVb = Wcat + (size_t)4 * H_ * H_;               // [8000][2304]
    unsigned short* ctxb = QKVb + (size_t)M_ * HC_;                  // [8000][768]

    // 1) fused x-prep + weight cast
    const int nprep = (int)(((size_t)M_ * H_ / 4 + (size_t)4 * H_ * H_ / 4 + 255) / 256);
    prep_all_kernel<<<nprep, 256, 0, stream>>>(feat, pos, level, xb, Wq, Wk, Wv, Wo, Wcat);
    // 2) QKV = x @ [Wq|Wk|Wv]^T + bias   (grid 63x18 = 1134, 512 thr)
    gemm_qkv5<<<63 * 18, 512, 0, stream>>>(xb, Wcat, bq, bk, bv, QKVb);
    // 3) banded attention -> ctx (bf16)
    attn_kernel<<<B_ * NH_ * 16, 256, 0, stream>>>(QKVb, ctxb, level);
    // 4) y = ctx @ Wo^T + bo + features  (grid 63x12 = 756, 256 thr)
    gemm_out4<<<63 * 12, 256, 0, stream>>>(ctxb, Wcat + (size_t)3 * H_ * H_, bo, feat, out);
    // 5) LayerNorm in place on d_out
    ln_kernel<<<M_, 256, 0, stream>>>(out, ln_g, ln_b);
}